// Round 10
// baseline (157.364 us; speedup 1.0000x reference)
//
#include <hip/hip_runtime.h>
#include <hip/hip_bf16.h>

#define B_ 8
#define N_ 256
#define H_ 128
#define E_ 32

typedef __bf16 bf16x8 __attribute__((ext_vector_type(8)));
typedef __bf16 bf16x4 __attribute__((ext_vector_type(4)));
typedef float f32x4 __attribute__((ext_vector_type(4)));

// round-to-nearest-even fp32 -> bf16
static __device__ __forceinline__ __bf16 f2bf(float f) {
    union { float f; unsigned int u; } a;
    a.f = f;
    const unsigned int r = a.u + 0x7FFFu + ((a.u >> 16) & 1u);
    union { unsigned short s; __bf16 b; } o;
    o.s = (unsigned short)(r >> 16);
    return o.b;
}

// ws layout (xbT stored bf16 so total = 776 KiB):
//   xbT  : bf16, elem [0, 262144)            = bytes [0, 524288)
//   W1T  : f32,  float-offset [131072, 163840)
//   W2T  : f32,  float-offset [163840, 196608)
//   Webf : bf16, float-offset 196608, 4096 elems (8 KiB)
#define W1T_OFF  131072
#define W2T_OFF  163840
#define WEBF_OFF 196608

// Prep: (a) xbT[b,h,j] = bf16(x[b,j,h] + be[h]), (b) W1T/W2T transposes,
// (c) We packed as per-lane bf16 MFMA B-fragments (one dwordx4 per tile).
__global__ __launch_bounds__(256) void prep_kernel(
    const float* __restrict__ x, const float* __restrict__ be,
    const float* __restrict__ W1, const float* __restrict__ W2,
    const float* __restrict__ We, float* __restrict__ ws)
{
    const int blk = blockIdx.x;
    if (blk == 320) {               // (c) We fragments: [quad][h][kk] bf16
        __bf16* Webf = (__bf16*)(ws + WEBF_OFF);
        for (int q = threadIdx.x; q < 512; q += 256) {
            const int quad = q >> 7, h = q & 127;
            bf16x8 t;
#pragma unroll
            for (int kk = 0; kk < 8; ++kk)
                t[kk] = f2bf(We[(quad * 8 + kk) * H_ + h]);
            *(bf16x8*)&Webf[q * 8] = t;
        }
        return;
    }
    __shared__ float tile[32][33];
    const int tx = threadIdx.x & 31, ty = threadIdx.x >> 5;   // ty 0..7
    if (blk < 256) {                // (a) per-batch x transpose, bf16 out
        const int b = blk >> 5, t = blk & 31;
        const float* src = x + (size_t)b * N_ * H_;
        __bf16* dst = (__bf16*)ws + (size_t)b * H_ * N_;
        const int r0 = (t >> 2) * 32, c0 = (t & 3) * 32;      // j0, h0
#pragma unroll
        for (int p = 0; p < 4; ++p)
            tile[ty + p * 8][tx] =
                src[(size_t)(r0 + ty + p * 8) * H_ + c0 + tx] + be[c0 + tx];
        __syncthreads();
#pragma unroll
        for (int p = 0; p < 4; ++p)
            dst[(size_t)(c0 + ty + p * 8) * N_ + r0 + tx] = f2bf(tile[tx][ty + p * 8]);
        return;
    }
    // (b) weight transposes (float dst)
    const float* src; float* dst; int R, C, r0, c0;
    if (blk < 288) {                // W1: 128x256 -> 256x128
        const int t = blk - 256;
        src = W1; dst = ws + W1T_OFF;
        R = 128; C = 256; r0 = (t >> 3) * 32; c0 = (t & 7) * 32;
    } else {                        // W2: 256x128 -> 128x256
        const int t = blk - 288;
        src = W2; dst = ws + W2T_OFF;
        R = 256; C = 128; r0 = (t >> 2) * 32; c0 = (t & 3) * 32;
    }
#pragma unroll
    for (int p = 0; p < 4; ++p)
        tile[ty + p * 8][tx] = src[(size_t)(r0 + ty + p * 8) * C + c0 + tx];
    __syncthreads();
#pragma unroll
    for (int p = 0; p < 4; ++p)
        dst[(size_t)(c0 + ty + p * 8) * R + r0 + tx] = tile[tx][ty + p * 8];
}

// Aggregation: one WG per (b,i)  ((256,2): only spill-free config — every
// higher-occupancy attempt spilled 130-280 MB scratch).
//   h[b,i,:] = x[b,i,:] + sum_j adj*relu(xb[b,j,:] + e[b,i,j,:]@We)
// r9 post-mortem: source-level load hoisting produced IDENTICAL codegen
// (VGPR 108, same dur) — the scheduler sinks the 8 xv loads into the
// epilogue, serializing 8 x ~200cyc L2 latency per chunk (matches the
// measured VALUBusy 18% = 340 compute / ~1940 total cyc per chunk).
// Fix: __builtin_amdgcn_sched_barrier(0) after the load block — a hard
// scheduling fence the compiler cannot re-sink across. Loads issue first,
// waits retire progressively during the MFMA/epilogue.
__global__ __launch_bounds__(256, 2) void agg_kernel(
    const int* __restrict__ adj, const float* __restrict__ e,
    const float* __restrict__ ws, const float* __restrict__ x,
    float* __restrict__ hout)
{
    __shared__ float red[4][128];
    const int bi   = blockIdx.x;      // b*256 + i
    const int b    = bi >> 8;
    const int tid  = threadIdx.x;
    const int w    = tid >> 6;
    const int lane = tid & 63;
    const int quad = lane >> 4;
    const int col  = lane & 15;

    // We B-fragments: 8 x dwordx4 from the pre-packed table.
    const __bf16* Webf = (const __bf16*)(ws + WEBF_OFF);
    bf16x8 bw[8];
#pragma unroll
    for (int ht = 0; ht < 8; ++ht)
        bw[ht] = *(const bf16x8*)&Webf[(quad * 128 + ht * 16 + col) * 8];

    float psum[8];
#pragma unroll
    for (int ht = 0; ht < 8; ++ht) psum[ht] = 0.0f;

    const size_t ebase   = (size_t)bi * (N_ * E_);
    const size_t adjbase = (size_t)bi * N_;
    const __bf16* xbase  = (const __bf16*)ws + (size_t)b * (H_ * N_) + col * N_;
    const f32x4 zero4 = {0.0f, 0.0f, 0.0f, 0.0f};

    // Prefetch chunk 0 (e: this lane's A-fragment; adj: int4).
    float4 a0, a1;
    int4   av;
    {
        const int j0 = w * 16;
        const float* ap = e + ebase + (size_t)(j0 + col) * E_ + quad * 8;
        a0 = *(const float4*)ap;
        a1 = *(const float4*)(ap + 4);
        av = *(const int4*)(adj + adjbase + j0 + quad * 4);
    }

#pragma unroll
    for (int c = 0; c < 4; ++c) {
        const int j0 = (c * 4 + w) * 16;
        const int jr = j0 + quad * 4;

        // (1) Issue ALL this chunk's xbT loads (8 independent dwordx2).
        const __bf16* xp = xbase + jr;
        bf16x4 xv[8];
#pragma unroll
        for (int ht = 0; ht < 8; ++ht)
            xv[ht] = *(const bf16x4*)(xp + (size_t)ht * 16 * N_);

        // (2) Convert current prefetch (frees a0/a1/av for reuse).
        bf16x8 af;
        af[0] = f2bf(a0.x); af[1] = f2bf(a0.y); af[2] = f2bf(a0.z); af[3] = f2bf(a0.w);
        af[4] = f2bf(a1.x); af[5] = f2bf(a1.y); af[6] = f2bf(a1.z); af[7] = f2bf(a1.w);
        float adjf[4];
        adjf[0] = av.x ? 1.0f : 0.0f;
        adjf[1] = av.y ? 1.0f : 0.0f;
        adjf[2] = av.z ? 1.0f : 0.0f;
        adjf[3] = av.w ? 1.0f : 0.0f;

        // (3) Issue next chunk's e/adj prefetch.
        if (c < 3) {
            const int j0n = ((c + 1) * 4 + w) * 16;
            const float* apn = e + ebase + (size_t)(j0n + col) * E_ + quad * 8;
            a0 = *(const float4*)apn;
            a1 = *(const float4*)(apn + 4);
            av = *(const int4*)(adj + adjbase + j0n + quad * 4);
        }

        // (4) Hard scheduling fence: nothing above may sink below, nothing
        // below may hoist above. Forces all loads in flight before compute.
        __builtin_amdgcn_sched_barrier(0);

        // (5) MFMA + epilogue; xv waits retire progressively per tile.
#pragma unroll
        for (int g = 0; g < 2; ++g) {
            f32x4 acc[4];
#pragma unroll
            for (int t = 0; t < 4; ++t)
                acc[t] = __builtin_amdgcn_mfma_f32_16x16x32_bf16(af, bw[g * 4 + t], zero4, 0, 0, 0);
#pragma unroll
            for (int t = 0; t < 4; ++t) {
                const int ht = g * 4 + t;
#pragma unroll
                for (int r = 0; r < 4; ++r)
                    psum[ht] += adjf[r] * fmaxf(acc[t][r] + (float)xv[ht][r], 0.0f);
            }
        }
    }

    // Quad reduce in-register, wave reduce via LDS; h = agg + x[b,i,:].
#pragma unroll
    for (int ht = 0; ht < 8; ++ht) {
        float v = psum[ht];
        v += __shfl_xor(v, 16);
        v += __shfl_xor(v, 32);
        if (lane < 16) red[w][ht * 16 + lane] = v;
    }
    __syncthreads();
    if (tid < 128) {
        const float aggv = red[0][tid] + red[1][tid] + red[2][tid] + red[3][tid];
        hout[(size_t)bi * H_ + tid] = aggv + x[(size_t)bi * H_ + tid];
    }
}

// MLP: out = relu(h@W1+b1)@W2 + b2, fp32, 8 rows/WG x 256 WGs.
// Weight L2 traffic: 256 WG x 262 KB = 67 MB. All weight loads f32x4 via
// transposed W1T/W2T. Reads h from d_out, overwrites the same 8 rows.
__global__ __launch_bounds__(256) void mlp_kernel(
    const float* __restrict__ ws, const float* __restrict__ b1,
    const float* __restrict__ b2, float* __restrict__ hio)
{
    __shared__ float hs[8][128];
    __shared__ float ts[8][256];
    __shared__ float part[8][2][128];
    const int tid = threadIdx.x;
    const int r0  = blockIdx.x * 8;

    ((f32x4*)hs)[tid] = ((const f32x4*)(hio + (size_t)r0 * H_))[tid];
    __syncthreads();

    // Layer 1: thread owns column tid for all 8 rows; W1T row = 128 floats.
    {
        const float* wrow = ws + W1T_OFF + (size_t)tid * 128;
        float acc[8] = {0.f, 0.f, 0.f, 0.f, 0.f, 0.f, 0.f, 0.f};
        for (int k = 0; k < 128; k += 4) {
            const f32x4 wv = *(const f32x4*)&wrow[k];
#pragma unroll
            for (int r = 0; r < 8; ++r) {
                const f32x4 hv = *(const f32x4*)&hs[r][k];   // LDS broadcast
                acc[r] += hv[0] * wv[0] + hv[1] * wv[1] + hv[2] * wv[2] + hv[3] * wv[3];
            }
        }
        const float bb = b1[tid];
#pragma unroll
        for (int r = 0; r < 8; ++r) ts[r][tid] = fmaxf(acc[r] + bb, 0.0f);
    }
    __syncthreads();

    // Layer 2: two threads per column (k split 128/128); W2T row = 256 floats.
    {
        const int c  = tid & 127;
        const int kb = (tid >> 7) * 128;
        const float* wrow = ws + W2T_OFF + (size_t)c * 256 + kb;
        float acc[8] = {0.f, 0.f, 0.f, 0.f, 0.f, 0.f, 0.f, 0.f};
        for (int k = 0; k < 128; k += 4) {
            const f32x4 wv = *(const f32x4*)&wrow[k];
#pragma unroll
            for (int r = 0; r < 8; ++r) {
                const f32x4 tv = *(const f32x4*)&ts[r][kb + k];  // 2-way bcast
                acc[r] += tv[0] * wv[0] + tv[1] * wv[1] + tv[2] * wv[2] + tv[3] * wv[3];
            }
        }
#pragma unroll
        for (int r = 0; r < 8; ++r) part[r][tid >> 7][c] = acc[r];
    }
    __syncthreads();
#pragma unroll
    for (int idx = tid; idx < 1024; idx += 256) {
        const int r = idx >> 7, c = idx & 127;
        hio[(size_t)(r0 + r) * H_ + c] = part[r][0][c] + part[r][1][c] + b2[c];
    }
}

extern "C" void kernel_launch(void* const* d_in, const int* in_sizes, int n_in,
                              void* d_out, int out_size, void* d_ws, size_t ws_size,
                              hipStream_t stream) {
    const float* x   = (const float*)d_in[0];
    const int*   adj = (const int*)  d_in[1];
    const float* e   = (const float*)d_in[2];
    const float* We  = (const float*)d_in[3];
    const float* be  = (const float*)d_in[4];
    const float* W1  = (const float*)d_in[5];
    const float* b1  = (const float*)d_in[6];
    const float* W2  = (const float*)d_in[7];
    const float* b2  = (const float*)d_in[8];
    float* out = (float*)d_out;
    float* ws  = (float*)d_ws;   // 776 KiB used (xbT bf16 + W1T + W2T + Webf)

    prep_kernel<<<dim3(321), dim3(256), 0, stream>>>(x, be, W1, W2, We, ws);
    agg_kernel<<<dim3(B_ * N_), dim3(256), 0, stream>>>(adj, e, ws, x, out);
    mlp_kernel<<<dim3(B_ * N_ / 8), dim3(256), 0, stream>>>(ws, b1, b2, out);
}

// Round 11
// 141.273 us; speedup vs baseline: 1.1139x; 1.1139x over previous
//
#include <hip/hip_runtime.h>
#include <hip/hip_bf16.h>

#define B_ 8
#define N_ 256
#define H_ 128
#define E_ 32
#define XLS_STRIDE 264   // bf16 elems/row: 256 + 8 pad (528 B, 8B-aligned rows)

typedef __bf16 bf16x8 __attribute__((ext_vector_type(8)));
typedef __bf16 bf16x4 __attribute__((ext_vector_type(4)));
typedef float f32x4 __attribute__((ext_vector_type(4)));

// round-to-nearest-even fp32 -> bf16
static __device__ __forceinline__ __bf16 f2bf(float f) {
    union { float f; unsigned int u; } a;
    a.f = f;
    const unsigned int r = a.u + 0x7FFFu + ((a.u >> 16) & 1u);
    union { unsigned short s; __bf16 b; } o;
    o.s = (unsigned short)(r >> 16);
    return o.b;
}

// ws layout (xbT stored bf16 so total = 776 KiB):
//   xbT  : bf16, elem [0, 262144)            = bytes [0, 524288)
//   W1T  : f32,  float-offset [131072, 163840)
//   W2T  : f32,  float-offset [163840, 196608)
//   Webf : bf16, float-offset 196608, 4096 elems (8 KiB)
#define W1T_OFF  131072
#define W2T_OFF  163840
#define WEBF_OFF 196608

// Prep: (a) xbT[b,h,j] = bf16(x[b,j,h] + be[h]), (b) W1T/W2T transposes,
// (c) We packed as per-lane bf16 MFMA B-fragments (one dwordx4 per tile).
__global__ __launch_bounds__(256) void prep_kernel(
    const float* __restrict__ x, const float* __restrict__ be,
    const float* __restrict__ W1, const float* __restrict__ W2,
    const float* __restrict__ We, float* __restrict__ ws)
{
    const int blk = blockIdx.x;
    if (blk == 320) {               // (c) We fragments: [quad][h][kk] bf16
        __bf16* Webf = (__bf16*)(ws + WEBF_OFF);
        for (int q = threadIdx.x; q < 512; q += 256) {
            const int quad = q >> 7, h = q & 127;
            bf16x8 t;
#pragma unroll
            for (int kk = 0; kk < 8; ++kk)
                t[kk] = f2bf(We[(quad * 8 + kk) * H_ + h]);
            *(bf16x8*)&Webf[q * 8] = t;
        }
        return;
    }
    __shared__ float tile[32][33];
    const int tx = threadIdx.x & 31, ty = threadIdx.x >> 5;   // ty 0..7
    if (blk < 256) {                // (a) per-batch x transpose, bf16 out
        const int b = blk >> 5, t = blk & 31;
        const float* src = x + (size_t)b * N_ * H_;
        __bf16* dst = (__bf16*)ws + (size_t)b * H_ * N_;
        const int r0 = (t >> 2) * 32, c0 = (t & 3) * 32;      // j0, h0
#pragma unroll
        for (int p = 0; p < 4; ++p)
            tile[ty + p * 8][tx] =
                src[(size_t)(r0 + ty + p * 8) * H_ + c0 + tx] + be[c0 + tx];
        __syncthreads();
#pragma unroll
        for (int p = 0; p < 4; ++p)
            dst[(size_t)(c0 + ty + p * 8) * N_ + r0 + tx] = f2bf(tile[tx][ty + p * 8]);
        return;
    }
    // (b) weight transposes (float dst)
    const float* src; float* dst; int R, C, r0, c0;
    if (blk < 288) {                // W1: 128x256 -> 256x128
        const int t = blk - 256;
        src = W1; dst = ws + W1T_OFF;
        R = 128; C = 256; r0 = (t >> 3) * 32; c0 = (t & 7) * 32;
    } else {                        // W2: 256x128 -> 128x256
        const int t = blk - 288;
        src = W2; dst = ws + W2T_OFF;
        R = 256; C = 128; r0 = (t >> 2) * 32; c0 = (t & 3) * 32;
    }
#pragma unroll
    for (int p = 0; p < 4; ++p)
        tile[ty + p * 8][tx] = src[(size_t)(r0 + ty + p * 8) * C + c0 + tx];
    __syncthreads();
#pragma unroll
    for (int p = 0; p < 4; ++p)
        dst[(size_t)(c0 + ty + p * 8) * R + r0 + tx] = tile[tx][ty + p * 8];
}

// Aggregation: one WG per (b,i)  ((256,2): only spill-free config).
//   h[b,i,:] = x[b,i,:] + sum_j adj*relu(xb[b,j,:] + e[b,i,j,:]@We)
// r9/r10 post-mortem: source scheduling (hoist, sched_barrier) produced
// identical codegen/perf — the 32 per-thread xv GLOBAL loads are the wall
// (8 x ~200-900cyc exposed waits per chunk at 2 waves/SIMD). r11 fix:
//  (1) stage the WG's entire xbT[b] slice (64 KB) into LDS once (16
//      coalesced 16B load+ds_write per thread; padded stride 264 bf16 caps
//      read aliasing ~4-way) -> all epilogue xv reads become ds_read_b64,
//      pipelined under the MFMAs via fine-grained lgkmcnt.
//  (2) e/adj prefetch depth 2 (~800cyc lead >= HBM ~900cyc), paid for by
//      the 16 regs freed from xv[8].
__global__ __launch_bounds__(256, 2) void agg_kernel(
    const int* __restrict__ adj, const float* __restrict__ e,
    const float* __restrict__ ws, const float* __restrict__ x,
    float* __restrict__ hout)
{
    __shared__ __bf16 xls[H_ * XLS_STRIDE];   // 66 KB staged xbT[b]
    __shared__ float red[4][128];
    const int bi   = blockIdx.x;      // b*256 + i
    const int b    = bi >> 8;
    const int tid  = threadIdx.x;
    const int w    = tid >> 6;
    const int lane = tid & 63;
    const int quad = lane >> 4;
    const int col  = lane & 15;

    const size_t ebase   = (size_t)bi * (N_ * E_);
    const size_t adjbase = (size_t)bi * N_;

    // (1) Depth-2 e/adj prefetch: issue the two HBM chunks FIRST so their
    // ~900cyc latency elapses during the LDS staging below.
    float4 a0v[2], a1v[2];
    int4   avv[2];
#pragma unroll
    for (int p = 0; p < 2; ++p) {
        const int j0 = (p * 4 + w) * 16;
        const float* ap = e + ebase + (size_t)(j0 + col) * E_ + quad * 8;
        a0v[p] = *(const float4*)ap;
        a1v[p] = *(const float4*)(ap + 4);
        avv[p] = *(const int4*)(adj + adjbase + j0 + quad * 4);
    }

    // (2) Stage xbT[b] (128 x 256 bf16) -> LDS, padded rows (264 bf16).
    {
        const __bf16* gx = (const __bf16*)ws + (size_t)b * (H_ * N_);
#pragma unroll 4
        for (int it = 0; it < 16; ++it) {
            const int k   = it * 256 + tid;       // 16B-chunk index
            const int row = k >> 5, cc = k & 31;
            const f32x4 v = *(const f32x4*)(gx + (size_t)row * 256 + cc * 8);
            *(f32x4*)&xls[row * XLS_STRIDE + cc * 8] = v;
        }
    }

    // (3) We B-fragments: 8 x dwordx4 from the pre-packed table (L2-hot).
    const __bf16* Webf = (const __bf16*)(ws + WEBF_OFF);
    bf16x8 bw[8];
#pragma unroll
    for (int ht = 0; ht < 8; ++ht)
        bw[ht] = *(const bf16x8*)&Webf[(quad * 128 + ht * 16 + col) * 8];

    float psum[8];
#pragma unroll
    for (int ht = 0; ht < 8; ++ht) psum[ht] = 0.0f;

    const f32x4 zero4 = {0.0f, 0.0f, 0.0f, 0.0f};

    __syncthreads();   // xls staging complete (also drains stage loads)

#pragma unroll
    for (int c = 0; c < 4; ++c) {
        const int s  = c & 1;
        const int jr = (c * 4 + w) * 16 + quad * 4;

        bf16x8 af;
        af[0] = f2bf(a0v[s].x); af[1] = f2bf(a0v[s].y);
        af[2] = f2bf(a0v[s].z); af[3] = f2bf(a0v[s].w);
        af[4] = f2bf(a1v[s].x); af[5] = f2bf(a1v[s].y);
        af[6] = f2bf(a1v[s].z); af[7] = f2bf(a1v[s].w);
        float adjf[4];
        adjf[0] = avv[s].x ? 1.0f : 0.0f;
        adjf[1] = avv[s].y ? 1.0f : 0.0f;
        adjf[2] = avv[s].z ? 1.0f : 0.0f;
        adjf[3] = avv[s].w ? 1.0f : 0.0f;

        // Refill this slot with chunk c+2 (stays 2 chunks ahead of use).
        if (c < 2) {
            const int j0n = ((c + 2) * 4 + w) * 16;
            const float* apn = e + ebase + (size_t)(j0n + col) * E_ + quad * 8;
            a0v[s] = *(const float4*)apn;
            a1v[s] = *(const float4*)(apn + 4);
            avv[s] = *(const int4*)(adj + adjbase + j0n + quad * 4);
        }

        // MFMA + epilogue; xv now from LDS (ds_read_b64, ~4-way alias max).
#pragma unroll
        for (int g = 0; g < 2; ++g) {
            f32x4 acc[4];
#pragma unroll
            for (int t = 0; t < 4; ++t)
                acc[t] = __builtin_amdgcn_mfma_f32_16x16x32_bf16(af, bw[g * 4 + t], zero4, 0, 0, 0);
#pragma unroll
            for (int t = 0; t < 4; ++t) {
                const int ht = g * 4 + t;
                const bf16x4 xv = *(const bf16x4*)&xls[(ht * 16 + col) * XLS_STRIDE + jr];
#pragma unroll
                for (int r = 0; r < 4; ++r)
                    psum[ht] += adjf[r] * fmaxf(acc[t][r] + (float)xv[r], 0.0f);
            }
        }
    }

    // Quad reduce in-register, wave reduce via LDS; h = agg + x[b,i,:].
#pragma unroll
    for (int ht = 0; ht < 8; ++ht) {
        float v = psum[ht];
        v += __shfl_xor(v, 16);
        v += __shfl_xor(v, 32);
        if (lane < 16) red[w][ht * 16 + lane] = v;
    }
    __syncthreads();
    if (tid < 128) {
        const float aggv = red[0][tid] + red[1][tid] + red[2][tid] + red[3][tid];
        hout[(size_t)bi * H_ + tid] = aggv + x[(size_t)bi * H_ + tid];
    }
}

// MLP: out = relu(h@W1+b1)@W2 + b2, fp32, 8 rows/WG x 256 WGs.
// Weight L2 traffic: 256 WG x 262 KB = 67 MB. All weight loads f32x4 via
// transposed W1T/W2T. Reads h from d_out, overwrites the same 8 rows.
__global__ __launch_bounds__(256) void mlp_kernel(
    const float* __restrict__ ws, const float* __restrict__ b1,
    const float* __restrict__ b2, float* __restrict__ hio)
{
    __shared__ float hs[8][128];
    __shared__ float ts[8][256];
    __shared__ float part[8][2][128];
    const int tid = threadIdx.x;
    const int r0  = blockIdx.x * 8;

    ((f32x4*)hs)[tid] = ((const f32x4*)(hio + (size_t)r0 * H_))[tid];
    __syncthreads();

    // Layer 1: thread owns column tid for all 8 rows; W1T row = 128 floats.
    {
        const float* wrow = ws + W1T_OFF + (size_t)tid * 128;
        float acc[8] = {0.f, 0.f, 0.f, 0.f, 0.f, 0.f, 0.f, 0.f};
        for (int k = 0; k < 128; k += 4) {
            const f32x4 wv = *(const f32x4*)&wrow[k];
#pragma unroll
            for (int r = 0; r < 8; ++r) {
                const f32x4 hv = *(const f32x4*)&hs[r][k];   // LDS broadcast
                acc[r] += hv[0] * wv[0] + hv[1] * wv[1] + hv[2] * wv[2] + hv[3] * wv[3];
            }
        }
        const float bb = b1[tid];
#pragma unroll
        for (int r = 0; r < 8; ++r) ts[r][tid] = fmaxf(acc[r] + bb, 0.0f);
    }
    __syncthreads();

    // Layer 2: two threads per column (k split 128/128); W2T row = 256 floats.
    {
        const int c  = tid & 127;
        const int kb = (tid >> 7) * 128;
        const float* wrow = ws + W2T_OFF + (size_t)c * 256 + kb;
        float acc[8] = {0.f, 0.f, 0.f, 0.f, 0.f, 0.f, 0.f, 0.f};
        for (int k = 0; k < 128; k += 4) {
            const f32x4 wv = *(const f32x4*)&wrow[k];
#pragma unroll
            for (int r = 0; r < 8; ++r) {
                const f32x4 tv = *(const f32x4*)&ts[r][kb + k];  // 2-way bcast
                acc[r] += tv[0] * wv[0] + tv[1] * wv[1] + tv[2] * wv[2] + tv[3] * wv[3];
            }
        }
#pragma unroll
        for (int r = 0; r < 8; ++r) part[r][tid >> 7][c] = acc[r];
    }
    __syncthreads();
#pragma unroll
    for (int idx = tid; idx < 1024; idx += 256) {
        const int r = idx >> 7, c = idx & 127;
        hio[(size_t)(r0 + r) * H_ + c] = part[r][0][c] + part[r][1][c] + b2[c];
    }
}

extern "C" void kernel_launch(void* const* d_in, const int* in_sizes, int n_in,
                              void* d_out, int out_size, void* d_ws, size_t ws_size,
                              hipStream_t stream) {
    const float* x   = (const float*)d_in[0];
    const int*   adj = (const int*)  d_in[1];
    const float* e   = (const float*)d_in[2];
    const float* We  = (const float*)d_in[3];
    const float* be  = (const float*)d_in[4];
    const float* W1  = (const float*)d_in[5];
    const float* b1  = (const float*)d_in[6];
    const float* W2  = (const float*)d_in[7];
    const float* b2  = (const float*)d_in[8];
    float* out = (float*)d_out;
    float* ws  = (float*)d_ws;   // 776 KiB used (xbT bf16 + W1T + W2T + Webf)

    prep_kernel<<<dim3(321), dim3(256), 0, stream>>>(x, be, W1, W2, We, ws);
    agg_kernel<<<dim3(B_ * N_), dim3(256), 0, stream>>>(adj, e, ws, x, out);
    mlp_kernel<<<dim3(B_ * N_ / 8), dim3(256), 0, stream>>>(ws, b1, b2, out);
}